// Round 1
// baseline (457.150 us; speedup 1.0000x reference)
//
#include <hip/hip_runtime.h>

#define N_NODES 100000
#define N_EDGES 800000
#define NF 81
#define NB 22
#define OC 64

// Skinny node GEMM: dst[n, :] = feat[n, :NF] @ w[:NF, :OC]
// Wave per node, lane = output channel. Weight column register-resident
// (full unroll -> constant indices -> stays in VGPRs). Feature row address
// scalarized so the compiler can batch s_loads off the VALU/VMEM pipes.
__global__ __launch_bounds__(256, 3) void k_node_mm(
    const float* __restrict__ feat, const float* __restrict__ w,
    float* __restrict__ dstp)
{
    const int lane   = threadIdx.x & 63;
    const int wid    = (int)((blockIdx.x * blockDim.x + threadIdx.x) >> 6);
    const int nwaves = (int)((gridDim.x * blockDim.x) >> 6);

    float wc[NF];
#pragma unroll
    for (int k = 0; k < NF; ++k) wc[k] = w[k * OC + lane];

    for (int n = wid; n < N_NODES; n += nwaves) {
        const int nu = __builtin_amdgcn_readfirstlane(n);
        const float* f = feat + (long)nu * NF;
        float acc = 0.f;
#pragma unroll
        for (int k = 0; k < NF; ++k) acc += f[k] * wc[k];
        dstp[(long)nu * OC + lane] = acc;
    }
}

// Edge kernel: wave per edge (grid-stride), lane = output channel.
// contrib = inv_d2*(PA[s] + PB[t]) + bond[e] @ w_n[81:103]
// PA[s] derived from PB[s] minus the first-3-feature contribution.
__global__ __launch_bounds__(256, 6) void k_edge(
    const float* __restrict__ feat, const float* __restrict__ bond,
    const float* __restrict__ w_n, const int* __restrict__ src,
    const int* __restrict__ dst, const float* __restrict__ pb,
    float* __restrict__ out)
{
    const int lane   = threadIdx.x & 63;
    const int wid    = (int)((blockIdx.x * blockDim.x + threadIdx.x) >> 6);
    const int nwaves = (int)((gridDim.x * blockDim.x) >> 6);

    // bond-part weight columns, loaded once per wave (L2-hot, coalesced)
    float wnb[NB];
#pragma unroll
    for (int j = 0; j < NB; ++j) wnb[j] = w_n[(NF + j) * OC + lane];
    const float w0 = w_n[0 * OC + lane];
    const float w1 = w_n[1 * OC + lane];
    const float w2 = w_n[2 * OC + lane];

    for (int e = wid; e < N_EDGES; e += nwaves) {
        const int eu = __builtin_amdgcn_readfirstlane(e);
        const int s = src[eu];
        const int t = dst[eu];

        // xyz of both endpoints: uniform addresses -> scalar loads
        const float sx = feat[(long)s * NF + 0];
        const float sy = feat[(long)s * NF + 1];
        const float sz = feat[(long)s * NF + 2];
        const float tx = feat[(long)t * NF + 0];
        const float ty = feat[(long)t * NF + 1];
        const float tz = feat[(long)t * NF + 2];

        const float dx = sx - tx, dy = sy - ty, dz = sz - tz;
        const float d2 = dx * dx + dy * dy + dz * dz;
        // ref: d = dist>0 ? dist : 0.01; scale = 1/d^2
        const float inv = (d2 > 0.f) ? __builtin_amdgcn_rcpf(d2) : 1.0e4f;

        // coalesced 256B row gathers
        const float pbs = pb[(long)s * OC + lane];
        const float pbt = pb[(long)t * OC + lane];
        const float pa  = pbs - (sx * w0 + sy * w1 + sz * w2);

        float acc = (pa + pbt) * inv;

        const float* be = bond + (long)eu * NB;  // uniform -> s_load batch
#pragma unroll
        for (int j = 0; j < NB; ++j) acc += be[j] * wnb[j];

        unsafeAtomicAdd(&out[(long)s * OC + lane], acc);
    }
}

extern "C" void kernel_launch(void* const* d_in, const int* in_sizes, int n_in,
                              void* d_out, int out_size, void* d_ws, size_t ws_size,
                              hipStream_t stream) {
    const float* feat = (const float*)d_in[0];
    const float* bond = (const float*)d_in[1];
    const float* w_s  = (const float*)d_in[2];
    const float* w_n  = (const float*)d_in[3];
    const int*   src  = (const int*)d_in[4];
    const int*   dstv = (const int*)d_in[5];
    float* out = (float*)d_out;
    float* pb  = (float*)d_ws;   // 100000*64*4 = 25.6 MB scratch

    // out = features @ w_s
    k_node_mm<<<1024, 256, 0, stream>>>(feat, w_s, out);
    // PB = features @ w_n[:81]  (w_n rows 0..80 are the leading rows)
    k_node_mm<<<1024, 256, 0, stream>>>(feat, w_n, pb);
    // out += segment_sum(edge contributions)
    k_edge<<<2048, 256, 0, stream>>>(feat, bond, w_n, src, dstv, pb, out);
}